// Round 16
// baseline (183.712 us; speedup 1.0000x reference)
//
#include <hip/hip_runtime.h>
#include <hip/hip_bf16.h>
#include <cstdint>

// LSTM cell: B=8192, D=1024, U=1024.
// z = [X|H](8192x2048) @ Wcat(2048x4096), gate interleave 16 in N, fused epilogue.
// GEMM: 256x128 tile, BK=32, 8 waves (4Mx2N), wave tile 64x64.
// CONVOY-BREAKER: 5 LDS buffers x 24KB = 120KB, stage-ahead-3, ONE barrier +
// counted vmcnt(3) per TWO windows; zero sync inside a super-window so waves
// drift and window w+1 reads overlap window w MFMAs. Write/read safety derived:
// stage of tile w+3 hits buf whose last reader is a full super-window behind.

using f32x4  = __attribute__((ext_vector_type(4))) float;
using short8 = __attribute__((ext_vector_type(8))) short;

__device__ __forceinline__ unsigned short f2bf(float f) {
  union { float f; unsigned int u; } v; v.f = f;
  unsigned int r = v.u + 0x7fffu + ((v.u >> 16) & 1u);  // RNE
  return (unsigned short)(r >> 16);
}
__device__ __forceinline__ float sigmoidf_fast(float x) { return 1.f / (1.f + __expf(-x)); }
__device__ __forceinline__ float tanhf_fast(float x)    { return 1.f - 2.f / (__expf(2.f * x) + 1.f); }

// ---------- A conversion: Abf[b][k] = bf16(k<1024 ? X[b][k] : H[b][k-1024])
__global__ void conv_a_kernel(const float* __restrict__ X, const float* __restrict__ H,
                              unsigned short* __restrict__ Abf) {
  int idx = blockIdx.x * blockDim.x + threadIdx.x;
  int b  = idx >> 8;
  int kq = (idx & 255) << 2;
  float4 x = *(const float4*)(X + (long)b * 1024 + kq);
  float4 h = *(const float4*)(H + (long)b * 1024 + kq);
  ushort4 xo, ho;
  xo.x = f2bf(x.x); xo.y = f2bf(x.y); xo.z = f2bf(x.z); xo.w = f2bf(x.w);
  ho.x = f2bf(h.x); ho.y = f2bf(h.y); ho.z = f2bf(h.z); ho.w = f2bf(h.w);
  *(ushort4*)(Abf + (long)b * 2048 + kq)        = xo;
  *(ushort4*)(Abf + (long)b * 2048 + 1024 + kq) = ho;
}

// ---------- B conversion: Bt[n][k] bf16, N-major, n = (u>>4)*64 + g*16 + (u&15)
__global__ void conv_b_kernel(const float* W_i, const float* U_i,
                              const float* W_f, const float* U_f,
                              const float* W_c, const float* U_c,
                              const float* W_o, const float* U_o,
                              unsigned short* __restrict__ Bt) {
  __shared__ float tile[64][65];
  int z = blockIdx.z;
  const float* src;
  switch (z) {
    case 0: src = W_i; break; case 1: src = U_i; break;
    case 2: src = W_f; break; case 3: src = U_f; break;
    case 4: src = W_c; break; case 5: src = U_c; break;
    case 6: src = W_o; break; default: src = U_o; break;
  }
  int g = z >> 1, s = z & 1;
  int k0 = blockIdx.x * 64;
  int u0 = blockIdx.y * 64;
  int t = threadIdx.x;
  int c = t & 63, r0 = t >> 6;
#pragma unroll
  for (int i = 0; i < 16; ++i) {
    int r = i * 4 + r0;
    tile[r][c] = src[(long)(k0 + r) * 1024 + u0 + c];
  }
  __syncthreads();
  int ul = t >> 2;
  int ks = (t & 3) * 16;
  unsigned short outv[16];
#pragma unroll
  for (int j = 0; j < 16; ++j) outv[j] = f2bf(tile[ks + j][ul]);
  long n   = 4L * u0 + (ul >> 4) * 64 + g * 16 + (ul & 15);
  long col = (long)s * 1024 + k0 + ks;
  uint4* dst = (uint4*)(Bt + n * 2048 + col);
  dst[0] = *(uint4*)(outv);
  dst[1] = *(uint4*)(outv + 8);
}

// ---------- fused GEMM + LSTM epilogue
// LDS buffer (12288 shorts = 24KB): A[256][32] at +0, B[128][32] at +8192. 5 bufs.
__global__ __launch_bounds__(512, 2) void lstm_gemm_kernel(
    const unsigned short* __restrict__ Abf,   // [8192][2048] bf16
    const unsigned short* __restrict__ Btbf,  // [4096][2048] bf16 (N-major)
    const float* __restrict__ b_i, const float* __restrict__ b_f,
    const float* __restrict__ b_c, const float* __restrict__ b_o,
    const float* __restrict__ c_tm1,
    float* __restrict__ outH, float* __restrict__ outC) {
  __shared__ unsigned short smem[5 * 12288];  // 120KB

  int bid = blockIdx.x;
  int swz = (bid & 7) * 128 + (bid >> 3);  // XCD swizzle, 1024 % 8 == 0
  int bm = swz >> 5;   // 32 m-blocks (M=8192/256)
  int bn = swz & 31;   // 32 n-blocks (N=4096/128)

  int t = threadIdx.x;
  int lane = t & 63;
  int w = t >> 6;           // 8 waves
  int wm = w >> 1;          // 0..3
  int wn = w & 1;           // 0..1
  int rl = lane & 15;
  int kg = lane >> 4;       // 0..3, 8-elem k-chunk

  // ---- frag ds_read offsets within a buffer (XOR chunk swizzle c ^= (row>>1)&3) ----
#define AOFFE(MI) (((wm * 64 + (MI) * 16 + rl) * 32) + \
    ((kg ^ (((wm * 64 + (MI) * 16 + rl) >> 1) & 3)) << 3))
#define BOFFE(NI) (8192 + ((wn * 64 + (NI) * 16 + rl) * 32) + \
    ((kg ^ (((wn * 64 + (NI) * 16 + rl) >> 1) & 3)) << 3))
  const int offA0 = AOFFE(0), offA1 = AOFFE(1), offA2 = AOFFE(2), offA3 = AOFFE(3);
  const int offB0 = BOFFE(0), offB1 = BOFFE(1), offB2 = BOFFE(2), offB3 = BOFFE(3);
#undef AOFFE
#undef BOFFE

  // ---- staging: linear LDS dest, inverse-swizzled global source ----
  int srow = t >> 2;                                  // 0..127
  int cbe  = ((t & 3) ^ ((srow >> 1) & 3)) << 3;      // source k-chunk (involution)
  const unsigned short* aS0 = Abf  + (long)(bm * 256 + srow) * 2048 + cbe;
  const unsigned short* aS1 = aS0 + 128L * 2048;
  const unsigned short* bS0 = Btbf + (long)(bn * 128 + srow) * 2048 + cbe;
  const int dA = t * 8;

#define GLL(SRC, DELM)                                                                     \
  __builtin_amdgcn_global_load_lds((const __attribute__((address_space(1))) void*)(SRC),   \
      (__attribute__((address_space(3))) void*)(&smem[DELM]), 16, 0, 0)
#define STAGE(SB, KOFF)                                                        \
  do {                                                                         \
    GLL(aS0 + (KOFF), (SB) * 12288 + dA);                                      \
    GLL(aS1 + (KOFF), (SB) * 12288 + 4096 + dA);                               \
    GLL(bS0 + (KOFF), (SB) * 12288 + 8192 + dA);                               \
  } while (0)
#define VMC(N) asm volatile("s_waitcnt vmcnt(" #N ")" ::: "memory")
#define BARS()                                                                 \
  do {                                                                         \
    __builtin_amdgcn_s_barrier();                                              \
    __builtin_amdgcn_sched_barrier(0);                                         \
  } while (0)

  f32x4 acc[4][4];
#pragma unroll
  for (int mi = 0; mi < 4; ++mi)
#pragma unroll
    for (int ni = 0; ni < 4; ++ni) acc[mi][ni] = (f32x4){0.f, 0.f, 0.f, 0.f};

  short8 aw0, aw1, aw2, aw3, bb0, bb1, bb2, bb3;

#define MF4(AF, MI)                                                                      \
  acc[MI][0] = __builtin_amdgcn_mfma_f32_16x16x32_bf16(AF, bb0, acc[MI][0], 0, 0, 0);    \
  acc[MI][1] = __builtin_amdgcn_mfma_f32_16x16x32_bf16(AF, bb1, acc[MI][1], 0, 0, 0);    \
  acc[MI][2] = __builtin_amdgcn_mfma_f32_16x16x32_bf16(AF, bb2, acc[MI][2], 0, 0, 0);    \
  acc[MI][3] = __builtin_amdgcn_mfma_f32_16x16x32_bf16(AF, bb3, acc[MI][3], 0, 0, 0);

// One window, NO sync: read buf RB, optionally stage tile into buf SB, 16 MFMA.
#define WINDOW(RB, SB, KOFF, DOST)                                             \
  {                                                                            \
    const unsigned short* S_ = smem + (RB) * 12288;                            \
    bb0 = *(const short8*)(S_ + offB0);                                        \
    bb1 = *(const short8*)(S_ + offB1);                                        \
    bb2 = *(const short8*)(S_ + offB2);                                        \
    bb3 = *(const short8*)(S_ + offB3);                                        \
    aw0 = *(const short8*)(S_ + offA0);                                        \
    aw1 = *(const short8*)(S_ + offA1);                                        \
    aw2 = *(const short8*)(S_ + offA2);                                        \
    aw3 = *(const short8*)(S_ + offA3);                                        \
    if (DOST) STAGE(SB, KOFF);                                                 \
    __builtin_amdgcn_s_setprio(1);                                             \
    MF4(aw0, 0) MF4(aw1, 1) MF4(aw2, 2) MF4(aw3, 3)                            \
    __builtin_amdgcn_s_setprio(0);                                             \
  }

  // ---- prologue: stage tiles 0,1,2 -> bufs 0,1,2; land 0,1 (keep 2 in flight) ----
  STAGE(0, 0);
  STAGE(1, 32);
  STAGE(2, 64);
  VMC(3);
  BARS();

  // ---- 6 periods of 10 windows (5 super-windows each); window w: RB=w%5,
  // stages tile w+3 -> buf (w+3)%5 at source (j+3)*32 from period base ----
  for (int g = 0; g < 6; ++g) {
    WINDOW(0, 3, 96,  1) WINDOW(1, 4, 128, 1) VMC(3); BARS();
    WINDOW(2, 0, 160, 1) WINDOW(3, 1, 192, 1) VMC(3); BARS();
    WINDOW(4, 2, 224, 1) WINDOW(0, 3, 256, 1) VMC(3); BARS();
    WINDOW(1, 4, 288, 1) WINDOW(2, 0, 320, 1) VMC(3); BARS();
    WINDOW(3, 1, 352, 1) WINDOW(4, 2, 384, 1) VMC(3); BARS();
    aS0 += 320; aS1 += 320; bS0 += 320;
  }
  // ---- tail: windows 60..63 (base at tile 60) ----
  WINDOW(0, 3, 96, 1)   // w60: stage tile 63 -> buf 3
  WINDOW(1, 0, 0, 0)    // w61
  VMC(0);
  BARS();
  WINDOW(2, 0, 0, 0)    // w62
  WINDOW(3, 0, 0, 0)    // w63
#undef WINDOW
#undef MF4
#undef BARS
#undef VMC
#undef STAGE
#undef GLL

  // ---- fused LSTM epilogue ----
  // Wave N-span = 64 cols = one u-block: u = nbase/4 + rl; gate = ni.
  int mbase = bm * 256 + wm * 64;
  int nbase = bn * 128 + wn * 64;
  int u = (nbase >> 2) + rl;
  float bi_v = b_i[u], bf_v = b_f[u], bc_v = b_c[u], bo_v = b_o[u];
  int rquad = (lane >> 4) << 2;
#pragma unroll
  for (int mi = 0; mi < 4; ++mi) {
#pragma unroll
    for (int j = 0; j < 4; ++j) {
      int brow = mbase + mi * 16 + rquad + j;
      float zi = acc[mi][0][j] + bi_v;
      float zf = acc[mi][1][j] + bf_v;
      float zc = acc[mi][2][j] + bc_v;
      float zo = acc[mi][3][j] + bo_v;
      float ig = sigmoidf_fast(zi);
      float fg = sigmoidf_fast(zf);
      float cg = tanhf_fast(zc);
      float og = sigmoidf_fast(zo);
      float cp = c_tm1[(long)brow * 1024 + u];
      float cn = fg * cp + ig * cg;
      float hn = og * tanhf_fast(cn);
      outH[(long)brow * 1024 + u] = hn;
      outC[(long)brow * 1024 + u] = cn;
    }
  }
}

extern "C" void kernel_launch(void* const* d_in, const int* in_sizes, int n_in,
                              void* d_out, int out_size, void* d_ws, size_t ws_size,
                              hipStream_t stream) {
  (void)in_sizes; (void)n_in; (void)out_size; (void)ws_size;
  const float* X   = (const float*)d_in[0];
  const float* Hst = (const float*)d_in[1];
  const float* Cst = (const float*)d_in[2];
  const float* W_i = (const float*)d_in[3];
  const float* U_i = (const float*)d_in[4];
  const float* b_i = (const float*)d_in[5];
  const float* W_f = (const float*)d_in[6];
  const float* U_f = (const float*)d_in[7];
  const float* b_f = (const float*)d_in[8];
  const float* W_c = (const float*)d_in[9];
  const float* U_c = (const float*)d_in[10];
  const float* b_c = (const float*)d_in[11];
  const float* W_o = (const float*)d_in[12];
  const float* U_o = (const float*)d_in[13];
  const float* b_o = (const float*)d_in[14];

  unsigned short* Abf  = (unsigned short*)d_ws;                        // 32 MB
  unsigned short* Btbf = (unsigned short*)((char*)d_ws + 33554432);    // 16 MB

  float* outH = (float*)d_out;
  float* outC = outH + 8192L * 1024;

  conv_a_kernel<<<8192, 256, 0, stream>>>(X, Hst, Abf);
  conv_b_kernel<<<dim3(16, 16, 8), 256, 0, stream>>>(W_i, U_i, W_f, U_f, W_c, U_c, W_o, U_o, Btbf);
  lstm_gemm_kernel<<<1024, 512, 0, stream>>>(Abf, Btbf, b_i, b_f, b_c, b_o, Cst, outH, outC);
}